// Round 6
// baseline (2742.737 us; speedup 1.0000x reference)
//
#include <hip/hip_runtime.h>

typedef __attribute__((ext_vector_type(8))) short bf16x8;
typedef __attribute__((ext_vector_type(4))) float f32x4;
typedef __attribute__((ext_vector_type(4))) unsigned int u32x4;
typedef __attribute__((ext_vector_type(4))) unsigned short u16x4;

#define NE 8
#define NT 2048   // tokens per expert (B*C)
#define NM 2048
#define NH 7168

__device__ __forceinline__ unsigned short f2bf(float f) {
    unsigned int u = __float_as_uint(f);
    return (unsigned short)((u + 0x7fffu + ((u >> 16) & 1u)) >> 16);  // RNE
}

__device__ __forceinline__ void gld16(const void* g, void* l) {
    __builtin_amdgcn_global_load_lds(
        (const __attribute__((address_space(1))) void*)g,
        (__attribute__((address_space(3))) void*)l, 16, 0, 0);
}

// ============================ conversion kernels ============================

__global__ __launch_bounds__(256) void convert_x_kernel(
        const float* __restrict__ in, unsigned short* __restrict__ out) {
    const int i = blockIdx.x * 256 + threadIdx.x;      // f32x4 index
    f32x4 a = ((const f32x4*)in)[i];
    ((u16x4*)out)[i] = (u16x4){f2bf(a[0]), f2bf(a[1]), f2bf(a[2]), f2bf(a[3])};
}

// w [E][R][C] fp32 -> wT [E][C][R] bf16 (transpose within expert), 64x64 LDS tiles.
__global__ __launch_bounds__(256) void convert_wT_kernel(
        const float* __restrict__ in, unsigned short* __restrict__ out,
        int R, int C) {
    const int t = threadIdx.x;
    const int e = blockIdx.y;
    const int tiles_c = C >> 6;
    const int tr = blockIdx.x / tiles_c, tc = blockIdx.x % tiles_c;

    const float* ip = in + (size_t)e * R * C + (size_t)(tr * 64) * C + tc * 64;
    unsigned short* op = out + (size_t)e * R * C + (size_t)(tc * 64) * R + tr * 64;

    __shared__ unsigned short tl[64][68];

    const int rr = t >> 4, c4 = (t & 15) * 4;
#pragma unroll
    for (int q = 0; q < 4; ++q) {
        const int r = q * 16 + rr;
        f32x4 v = *(const f32x4*)(ip + (size_t)r * C + c4);
        *(u16x4*)&tl[r][c4] = (u16x4){f2bf(v[0]), f2bf(v[1]), f2bf(v[2]), f2bf(v[3])};
    }
    __syncthreads();
#pragma unroll
    for (int q = 0; q < 4; ++q) {
        const int oc = q * 16 + rr;          // output row = input col
        u16x4 v = (u16x4){tl[c4][oc], tl[c4 + 1][oc], tl[c4 + 2][oc], tl[c4 + 3][oc]};
        *(u16x4*)(op + (size_t)oc * R + c4) = v;
    }
}

// ============== GEMM1 (bf16): hidden = silu(xb*w1T^T)*(xb*w3T^T) ==============
// R2 schedule (best measured: stage -> sync -> compute -> sync, single buffer)
// + frag-major LDS (0 bank conflicts, r4/r5 verified) + BK=64 (halves the
// per-kernel drain count: NK 64 -> 32).
// Fragment-major: each 16x32 MFMA fragment = 1KB contiguous, lane l owns bytes
// [l*16, l*16+16). Tile = 16 frags: offset (ksub*8 + fr)*512 shorts,
// fr = row/16 (0..7), ksub = k-half (0..1).
__global__ __launch_bounds__(256, 2) void gemm1b_kernel(
        const unsigned short* __restrict__ xb, const unsigned short* __restrict__ w1t,
        const unsigned short* __restrict__ w3t, unsigned short* __restrict__ hid) {
    const int tid = threadIdx.x;
    const int lane = tid & 63, wv = tid >> 6;
    const int e = blockIdx.y;
    const int d = blockIdx.x;                       // 0..895
    const int l = (d & 7) * 112 + (d >> 3);         // XCD-contiguous, bijective
    const int hn = l >> 4, tm = l & 15;             // hn: H tile (56), tm: token tile (16)

    const unsigned short* xg = xb + (size_t)(e * NT + tm * 128) * NM;
    const unsigned short* g1 = w1t + (size_t)e * NH * NM + (size_t)(hn * 128) * NM;
    const unsigned short* g3 = w3t + (size_t)e * NH * NM + (size_t)(hn * 128) * NM;
    unsigned short* hg = hid + (size_t)(e * NT + tm * 128) * NH + hn * 128;

    // 3 tiles x 16 frags x 512 shorts = 48 KiB, single-buffered
    __shared__ __align__(16) unsigned short lds[3 * 8192];
    unsigned short* sA  = lds;
    unsigned short* sB1 = lds + 8192;
    unsigned short* sB3 = lds + 2 * 8192;

    const int fr0 = 2 * wv;                // this wave stages frags fr0, fr0+1
    const int frow = lane & 15;            // fragment row (or B col)
    const int fks = (lane >> 4) * 8;       // k element offset within 32

    const int lr = lane & 15, lq = lane >> 4;
    const int r0w = (wv >> 1) * 64, c0w = (wv & 1) * 64;
    const int fA = (wv >> 1) * 4;          // first A frag this wave consumes
    const int fB = (wv & 1) * 4;           // first B frag this wave consumes
    const int la = lane * 8;               // shorts: lane*16B

    f32x4 accg[4][4], accu[4][4];
#pragma unroll
    for (int m = 0; m < 4; ++m)
#pragma unroll
        for (int n = 0; n < 4; ++n) {
            accg[m][n] = (f32x4){0.f, 0.f, 0.f, 0.f};
            accu[m][n] = (f32x4){0.f, 0.f, 0.f, 0.f};
        }

    const int srow = (size_t)(fr0 * 16 + frow);

    auto stage = [&](int ks) {
        const int k0 = ks * 64;
#pragma unroll
        for (int ksub = 0; ksub < 2; ++ksub) {
            const int fo = (ksub * 8 + fr0) * 512;
            const unsigned short* pa = xg + (size_t)srow * NM + k0 + ksub * 32 + fks;
            gld16(pa,           sA + fo);
            gld16(pa + 16 * NM, sA + fo + 512);
            const unsigned short* p1 = g1 + (size_t)srow * NM + k0 + ksub * 32 + fks;
            gld16(p1,           sB1 + fo);
            gld16(p1 + 16 * NM, sB1 + fo + 512);
            const unsigned short* p3 = g3 + (size_t)srow * NM + k0 + ksub * 32 + fks;
            gld16(p3,           sB3 + fo);
            gld16(p3 + 16 * NM, sB3 + fo + 512);
        }
    };

    auto compute = [&]() {
#pragma unroll
        for (int ksub = 0; ksub < 2; ++ksub) {
            const int ko = ksub * 8;
            bf16x8 af[4], b1f[4], b3f[4];
#pragma unroll
            for (int m = 0; m < 4; ++m)
                af[m] = *(const bf16x8*)(sA + (ko + fA + m) * 512 + la);
#pragma unroll
            for (int n = 0; n < 4; ++n) {
                b1f[n] = *(const bf16x8*)(sB1 + (ko + fB + n) * 512 + la);
                b3f[n] = *(const bf16x8*)(sB3 + (ko + fB + n) * 512 + la);
            }
#pragma unroll
            for (int m = 0; m < 4; ++m)
#pragma unroll
                for (int n = 0; n < 4; ++n) {
                    accg[m][n] = __builtin_amdgcn_mfma_f32_16x16x32_bf16(af[m], b1f[n], accg[m][n], 0, 0, 0);
                    accu[m][n] = __builtin_amdgcn_mfma_f32_16x16x32_bf16(af[m], b3f[n], accu[m][n], 0, 0, 0);
                }
        }
    };

    const int NK = NM / 64;                // 32
    for (int ks = 0; ks < NK; ++ks) {
        stage(ks);
        __syncthreads();                   // drains this wave's loads, publishes tile
        compute();
        __syncthreads();                   // all waves done reading before overwrite
    }

    // epilogue: silu(gate) * up -> bf16 hidden
#pragma unroll
    for (int m = 0; m < 4; ++m)
#pragma unroll
        for (int n = 0; n < 4; ++n)
#pragma unroll
            for (int i = 0; i < 4; ++i) {
                const float g = accg[m][n][i];
                const float u = accu[m][n][i];
                const float s = g / (1.f + __expf(-g));
                const int r = r0w + m * 16 + lq * 4 + i;
                const int c = c0w + n * 16 + lr;
                hg[(size_t)r * NH + c] = f2bf(s * u);
            }
}

// ================= GEMM2 (bf16): out = hid * w2T^T, fp32 out =================
// hid [E*T][H], w2T [E][M][H], out [E*T][M]. Same structure, BK=64, NK=112.
__global__ __launch_bounds__(256, 2) void gemm2b_kernel(
        const unsigned short* __restrict__ hid, const unsigned short* __restrict__ w2t,
        float* __restrict__ out) {
    const int tid = threadIdx.x;
    const int lane = tid & 63, wv = tid >> 6;
    const int e = blockIdx.y;
    const int d = blockIdx.x;                      // 0..255
    const int l = (d & 7) * 32 + (d >> 3);
    const int mn = l >> 4, tm = l & 15;

    const unsigned short* ag = hid + (size_t)(e * NT + tm * 128) * NH;
    const unsigned short* wg = w2t + (size_t)e * NM * NH + (size_t)(mn * 128) * NH;
    float* og = out + (size_t)(e * NT + tm * 128) * NM + mn * 128;

    // 2 tiles x 16 frags x 512 shorts = 32 KiB, single-buffered
    __shared__ __align__(16) unsigned short lds[2 * 8192];
    unsigned short* sA = lds;
    unsigned short* sB = lds + 8192;

    const int fr0 = 2 * wv;
    const int frow = lane & 15;
    const int fks = (lane >> 4) * 8;

    const int lr = lane & 15, lq = lane >> 4;
    const int r0w = (wv >> 1) * 64, c0w = (wv & 1) * 64;
    const int fA = (wv >> 1) * 4;
    const int fB = (wv & 1) * 4;
    const int la = lane * 8;

    f32x4 acc[4][4];
#pragma unroll
    for (int m = 0; m < 4; ++m)
#pragma unroll
        for (int n = 0; n < 4; ++n) acc[m][n] = (f32x4){0.f, 0.f, 0.f, 0.f};

    const int srow = fr0 * 16 + frow;

    auto stage = [&](int ks) {
        const int k0 = ks * 64;
#pragma unroll
        for (int ksub = 0; ksub < 2; ++ksub) {
            const int fo = (ksub * 8 + fr0) * 512;
            const unsigned short* pa = ag + (size_t)srow * NH + k0 + ksub * 32 + fks;
            gld16(pa,           sA + fo);
            gld16(pa + 16 * NH, sA + fo + 512);
            const unsigned short* pb = wg + (size_t)srow * NH + k0 + ksub * 32 + fks;
            gld16(pb,           sB + fo);
            gld16(pb + 16 * NH, sB + fo + 512);
        }
    };

    auto compute = [&]() {
#pragma unroll
        for (int ksub = 0; ksub < 2; ++ksub) {
            const int ko = ksub * 8;
            bf16x8 af[4], bf[4];
#pragma unroll
            for (int m = 0; m < 4; ++m)
                af[m] = *(const bf16x8*)(sA + (ko + fA + m) * 512 + la);
#pragma unroll
            for (int n = 0; n < 4; ++n)
                bf[n] = *(const bf16x8*)(sB + (ko + fB + n) * 512 + la);
#pragma unroll
            for (int m = 0; m < 4; ++m)
#pragma unroll
                for (int n = 0; n < 4; ++n)
                    acc[m][n] = __builtin_amdgcn_mfma_f32_16x16x32_bf16(af[m], bf[n], acc[m][n], 0, 0, 0);
        }
    };

    const int NK = NH / 64;                // 112
    for (int ks = 0; ks < NK; ++ks) {
        stage(ks);
        __syncthreads();
        compute();
        __syncthreads();
    }

#pragma unroll
    for (int m = 0; m < 4; ++m)
#pragma unroll
        for (int n = 0; n < 4; ++n)
#pragma unroll
            for (int i = 0; i < 4; ++i) {
                const int r = r0w + m * 16 + lq * 4 + i;
                const int c = c0w + n * 16 + lr;
                og[(size_t)r * NM + c] = acc[m][n][i];
            }
}

// ===================== fallback (round-1, fused-convert) =====================
#define ROWB 80
#define TILEB (128 * ROWB)

__global__ __launch_bounds__(256, 2) void gemm1_fb_kernel(
        const float* __restrict__ x, const float* __restrict__ w1,
        const float* __restrict__ w3, unsigned short* __restrict__ hid) {
    const int tid = threadIdx.x;
    const int e = blockIdx.y;
    const int d = blockIdx.x;
    const int l = (d & 7) * 112 + (d >> 3);
    const int hn = l >> 4, tm = l & 15;

    const float* xg  = x  + (size_t)(e * NT + tm * 128) * NM;
    const float* w1g = w1 + (size_t)e * NM * NH + hn * 128;
    const float* w3g = w3 + (size_t)e * NM * NH + hn * 128;
    unsigned short* hg = hid + (size_t)(e * NT + tm * 128) * NH + hn * 128;

    __shared__ __align__(16) unsigned char lds[2 * 3 * TILEB];

    const int a_r = tid >> 3, a_c4 = tid & 7;
    const int w_kq = (tid >> 2) & 7;
    const int w_cg = ((tid >> 5) << 2) | (tid & 3);

    const int lane = tid & 63;
    const int wv = tid >> 6;
    const int r0w = (wv >> 1) * 64, c0w = (wv & 1) * 64;
    const int lr = lane & 15, lq = lane >> 4;

    f32x4 accg[4][4], accu[4][4];
#pragma unroll
    for (int m = 0; m < 4; ++m)
#pragma unroll
        for (int n = 0; n < 4; ++n) {
            accg[m][n] = (f32x4){0.f, 0.f, 0.f, 0.f};
            accu[m][n] = (f32x4){0.f, 0.f, 0.f, 0.f};
        }

    f32x4 la0, la1, la2, la3;
    f32x4 l10, l11, l12, l13, l30, l31, l32, l33;

    auto stage_load = [&](int ks) {
        const int k0 = ks * 32;
        const float* pa = xg + (size_t)a_r * NM + k0 + a_c4 * 4;
        la0 = *(const f32x4*)(pa);
        la1 = *(const f32x4*)(pa + 32 * NM);
        la2 = *(const f32x4*)(pa + 64 * NM);
        la3 = *(const f32x4*)(pa + 96 * NM);
        const float* p1 = w1g + (size_t)(k0 + w_kq * 4) * NH + w_cg * 4;
        l10 = *(const f32x4*)(p1);
        l11 = *(const f32x4*)(p1 + NH);
        l12 = *(const f32x4*)(p1 + 2 * NH);
        l13 = *(const f32x4*)(p1 + 3 * NH);
        const float* p3 = w3g + (size_t)(k0 + w_kq * 4) * NH + w_cg * 4;
        l30 = *(const f32x4*)(p3);
        l31 = *(const f32x4*)(p3 + NH);
        l32 = *(const f32x4*)(p3 + 2 * NH);
        l33 = *(const f32x4*)(p3 + 3 * NH);
    };

    auto stage_write = [&](int buf) {
        unsigned char* base = lds + buf * (3 * TILEB);
        unsigned char* pa = base + a_r * ROWB + a_c4 * 8;
        *(u16x4*)(pa)             = (u16x4){f2bf(la0[0]), f2bf(la0[1]), f2bf(la0[2]), f2bf(la0[3])};
        *(u16x4*)(pa + 32 * ROWB) = (u16x4){f2bf(la1[0]), f2bf(la1[1]), f2bf(la1[2]), f2bf(la1[3])};
        *(u16x4*)(pa + 64 * ROWB) = (u16x4){f2bf(la2[0]), f2bf(la2[1]), f2bf(la2[2]), f2bf(la2[3])};
        *(u16x4*)(pa + 96 * ROWB) = (u16x4){f2bf(la3[0]), f2bf(la3[1]), f2bf(la3[2]), f2bf(la3[3])};
        unsigned char* pw1 = base + TILEB + w_kq * 8;
#pragma unroll
        for (int j = 0; j < 4; ++j) {
            const int c = w_cg * 4 + j;
            *(u16x4*)(pw1 + c * ROWB) =
                (u16x4){f2bf(l10[j]), f2bf(l11[j]), f2bf(l12[j]), f2bf(l13[j])};
        }
        unsigned char* pw3 = base + 2 * TILEB + w_kq * 8;
#pragma unroll
        for (int j = 0; j < 4; ++j) {
            const int c = w_cg * 4 + j;
            *(u16x4*)(pw3 + c * ROWB) =
                (u16x4){f2bf(l30[j]), f2bf(l31[j]), f2bf(l32[j]), f2bf(l33[j])};
        }
    };

    auto compute = [&](int buf) {
        const unsigned char* base = lds + buf * (3 * TILEB);
        bf16x8 af[4], b1f[4], b3f[4];
#pragma unroll
        for (int m = 0; m < 4; ++m)
            af[m] = *(const bf16x8*)(base + (r0w + m * 16 + lr) * ROWB + lq * 16);
#pragma unroll
        for (int n = 0; n < 4; ++n) {
            b1f[n] = *(const bf16x8*)(base + TILEB + (c0w + n * 16 + lr) * ROWB + lq * 16);
            b3f[n] = *(const bf16x8*)(base + 2 * TILEB + (c0w + n * 16 + lr) * ROWB + lq * 16);
        }
#pragma unroll
        for (int m = 0; m < 4; ++m)
#pragma unroll
            for (int n = 0; n < 4; ++n) {
                accg[m][n] = __builtin_amdgcn_mfma_f32_16x16x32_bf16(af[m], b1f[n], accg[m][n], 0, 0, 0);
                accu[m][n] = __builtin_amdgcn_mfma_f32_16x16x32_bf16(af[m], b3f[n], accu[m][n], 0, 0, 0);
            }
    };

    stage_load(0);
    stage_write(0);
    __syncthreads();
    int cur = 0;
    const int NK = NM / 32;
    for (int ks = 0; ks < NK; ++ks) {
        const bool more = (ks + 1 < NK);
        if (more) stage_load(ks + 1);
        compute(cur);
        if (more) {
            stage_write(cur ^ 1);
            __syncthreads();
        }
        cur ^= 1;
    }

#pragma unroll
    for (int m = 0; m < 4; ++m)
#pragma unroll
        for (int n = 0; n < 4; ++n)
#pragma unroll
            for (int i = 0; i < 4; ++i) {
                const float g = accg[m][n][i];
                const float u = accu[m][n][i];
                const float s = g / (1.f + __expf(-g));
                const int r = r0w + m * 16 + lq * 4 + i;
                const int c = c0w + n * 16 + lr;
                hg[(size_t)r * NH + c] = f2bf(s * u);
            }
}

__global__ __launch_bounds__(256, 2) void gemm2_fb_kernel(
        const unsigned short* __restrict__ hid, const float* __restrict__ w2,
        float* __restrict__ out) {
    const int tid = threadIdx.x;
    const int e = blockIdx.y;
    const int d = blockIdx.x;
    const int l = (d & 7) * 32 + (d >> 3);
    const int mn = l >> 4, tm = l & 15;

    const unsigned short* ag = hid + (size_t)(e * NT + tm * 128) * NH;
    const float* wg = w2 + (size_t)e * NH * NM + mn * 128;
    float* og = out + (size_t)(e * NT + tm * 128) * NM + mn * 128;

    __shared__ __align__(16) unsigned char lds[2 * 2 * TILEB];

    const int a_row = tid >> 2, a_ch = tid & 3;
    const int w_kq = (tid >> 2) & 7;
    const int w_cg = ((tid >> 5) << 2) | (tid & 3);

    const int lane = tid & 63;
    const int wv = tid >> 6;
    const int r0w = (wv >> 1) * 64, c0w = (wv & 1) * 64;
    const int lr = lane & 15, lq = lane >> 4;

    f32x4 acc[4][4];
#pragma unroll
    for (int m = 0; m < 4; ++m)
#pragma unroll
        for (int n = 0; n < 4; ++n) acc[m][n] = (f32x4){0.f, 0.f, 0.f, 0.f};

    u32x4 lau0, lau1;
    f32x4 lw0, lw1, lw2, lw3;

    auto stage_load = [&](int ks) {
        const int k0 = ks * 32;
        lau0 = *(const u32x4*)(ag + (size_t)a_row * NH + k0 + a_ch * 8);
        lau1 = *(const u32x4*)(ag + (size_t)(a_row + 64) * NH + k0 + a_ch * 8);
        const float* p = wg + (size_t)(k0 + w_kq * 4) * NM + w_cg * 4;
        lw0 = *(const f32x4*)(p);
        lw1 = *(const f32x4*)(p + NM);
        lw2 = *(const f32x4*)(p + 2 * NM);
        lw3 = *(const f32x4*)(p + 3 * NM);
    };

    auto stage_write = [&](int buf) {
        unsigned char* base = lds + buf * (2 * TILEB);
        *(u32x4*)(base + a_row * ROWB + a_ch * 16) = lau0;
        *(u32x4*)(base + (a_row + 64) * ROWB + a_ch * 16) = lau1;
        unsigned char* pw = base + TILEB + w_kq * 8;
#pragma unroll
        for (int j = 0; j < 4; ++j) {
            const int c = w_cg * 4 + j;
            *(u16x4*)(pw + c * ROWB) =
                (u16x4){f2bf(lw0[j]), f2bf(lw1[j]), f2bf(lw2[j]), f2bf(lw3[j])};
        }
    };

    auto compute = [&](int buf) {
        const unsigned char* base = lds + buf * (2 * TILEB);
        bf16x8 af[4], bf[4];
#pragma unroll
        for (int m = 0; m < 4; ++m)
            af[m] = *(const bf16x8*)(base + (r0w + m * 16 + lr) * ROWB + lq * 16);
#pragma unroll
        for (int n = 0; n < 4; ++n)
            bf[n] = *(const bf16x8*)(base + TILEB + (c0w + n * 16 + lr) * ROWB + lq * 16);
#pragma unroll
        for (int m = 0; m < 4; ++m)
#pragma unroll
            for (int n = 0; n < 4; ++n)
                acc[m][n] = __builtin_amdgcn_mfma_f32_16x16x32_bf16(af[m], bf[n], acc[m][n], 0, 0, 0);
    };

    stage_load(0);
    stage_write(0);
    __syncthreads();
    int cur = 0;
    const int NK = NH / 32;
    for (int ks = 0; ks < NK; ++ks) {
        const bool more = (ks + 1 < NK);
        if (more) stage_load(ks + 1);
        compute(cur);
        if (more) {
            stage_write(cur ^ 1);
            __syncthreads();
        }
        cur ^= 1;
    }

#pragma unroll
    for (int m = 0; m < 4; ++m)
#pragma unroll
        for (int n = 0; n < 4; ++n)
#pragma unroll
            for (int i = 0; i < 4; ++i) {
                const int r = r0w + m * 16 + lq * 4 + i;
                const int c = c0w + n * 16 + lr;
                og[(size_t)r * NM + c] = acc[m][n][i];
            }
}

// ================================ launcher ================================

extern "C" void kernel_launch(void* const* d_in, const int* in_sizes, int n_in,
                              void* d_out, int out_size, void* d_ws, size_t ws_size,
                              hipStream_t stream) {
    const float* x  = (const float*)d_in[0];
    const float* w1 = (const float*)d_in[1];
    const float* w2 = (const float*)d_in[2];
    const float* w3 = (const float*)d_in[3];
    float* out = (float*)d_out;

    const size_t XB_SZ  = (size_t)NE * NT * NM * 2;   //  64 MiB
    const size_t WT_SZ  = (size_t)NE * NM * NH * 2;   // 224 MiB
    const size_t HID_SZ = (size_t)NE * NT * NH * 2;   // 224 MiB
    const size_t NEED = XB_SZ + 2 * WT_SZ + HID_SZ;   // 736 MiB

    if (ws_size >= NEED) {
        unsigned char* ws = (unsigned char*)d_ws;
        unsigned short* xb  = (unsigned short*)(ws);
        unsigned short* w1t = (unsigned short*)(ws + XB_SZ);
        unsigned short* w3t = (unsigned short*)(ws + XB_SZ + WT_SZ);
        unsigned short* hidb = (unsigned short*)(ws + XB_SZ + 2 * WT_SZ);
        unsigned short* w2t = (unsigned short*)(ws);  // reuses xb/w1t after gemm1

        convert_x_kernel<<<dim3((NE * NT * NM) / 1024), 256, 0, stream>>>(x, xb);
        convert_wT_kernel<<<dim3((NM / 64) * (NH / 64), NE), 256, 0, stream>>>(w1, w1t, NM, NH);
        convert_wT_kernel<<<dim3((NM / 64) * (NH / 64), NE), 256, 0, stream>>>(w3, w3t, NM, NH);
        gemm1b_kernel<<<dim3(896, NE), 256, 0, stream>>>(xb, w1t, w3t, hidb);
        convert_wT_kernel<<<dim3((NH / 64) * (NM / 64), NE), 256, 0, stream>>>(w2, w2t, NH, NM);
        gemm2b_kernel<<<dim3(256, NE), 256, 0, stream>>>(hidb, w2t, out);
    } else {
        unsigned short* hid = (unsigned short*)d_ws;
        gemm1_fb_kernel<<<dim3(896, NE), 256, 0, stream>>>(x, w1, w3, hid);
        gemm2_fb_kernel<<<dim3(256, NE), 256, 0, stream>>>(hid, w2, out);
    }
}

// Round 8
// 1936.733 us; speedup vs baseline: 1.4162x; 1.4162x over previous
//
#include <hip/hip_runtime.h>

typedef __attribute__((ext_vector_type(8))) short bf16x8;
typedef __attribute__((ext_vector_type(4))) float f32x4;
typedef __attribute__((ext_vector_type(4))) unsigned int u32x4;
typedef __attribute__((ext_vector_type(4))) unsigned short u16x4;

#define NE 8
#define NT 2048   // tokens per expert (B*C)
#define NM 2048
#define NH 7168

// Raw barrier (no implicit vmcnt(0) drain) + counted vmcnt waits.
#define BAR() asm volatile("s_barrier" ::: "memory")
#define WAITV(N) asm volatile("s_waitcnt vmcnt(" #N ")" ::: "memory")

__device__ __forceinline__ unsigned short f2bf(float f) {
    unsigned int u = __float_as_uint(f);
    return (unsigned short)((u + 0x7fffu + ((u >> 16) & 1u)) >> 16);  // RNE
}

__device__ __forceinline__ void gld16(const void* g, void* l) {
    __builtin_amdgcn_global_load_lds(
        (const __attribute__((address_space(1))) void*)g,
        (__attribute__((address_space(3))) void*)l, 16, 0, 0);
}

// ============================ conversion kernels ============================

__global__ __launch_bounds__(256) void convert_x_kernel(
        const float* __restrict__ in, unsigned short* __restrict__ out) {
    const int i = blockIdx.x * 256 + threadIdx.x;      // f32x4 index
    f32x4 a = ((const f32x4*)in)[i];
    ((u16x4*)out)[i] = (u16x4){f2bf(a[0]), f2bf(a[1]), f2bf(a[2]), f2bf(a[3])};
}

// w [E][R][C] fp32 -> wT [E][C][R] bf16 (plain transpose), 64x64 LDS tiles.
__global__ __launch_bounds__(256) void convert_wT_kernel(
        const float* __restrict__ in, unsigned short* __restrict__ out,
        int R, int C) {
    const int t = threadIdx.x;
    const int e = blockIdx.y;
    const int tiles_c = C >> 6;
    const int tr = blockIdx.x / tiles_c, tc = blockIdx.x % tiles_c;

    const float* ip = in + (size_t)e * R * C + (size_t)(tr * 64) * C + tc * 64;
    unsigned short* op = out + (size_t)e * R * C + (size_t)(tc * 64) * R + tr * 64;

    __shared__ unsigned short tl[64][68];

    const int rr = t >> 4, c4 = (t & 15) * 4;
#pragma unroll
    for (int q = 0; q < 4; ++q) {
        const int r = q * 16 + rr;
        f32x4 v = *(const f32x4*)(ip + (size_t)r * C + c4);
        *(u16x4*)&tl[r][c4] = (u16x4){f2bf(v[0]), f2bf(v[1]), f2bf(v[2]), f2bf(v[3])};
    }
    __syncthreads();
#pragma unroll
    for (int q = 0; q < 4; ++q) {
        const int oc = q * 16 + rr;          // output row = input col
        u16x4 v = (u16x4){tl[c4][oc], tl[c4 + 1][oc], tl[c4 + 2][oc], tl[c4 + 3][oc]};
        *(u16x4*)(op + (size_t)oc * R + c4) = v;
    }
}

// w1,w3 [E][M][H] fp32 -> wcat [E][2H][M] bf16, transposed + 16-row interleaved:
// wcat row = 32*(h>>4) + 16*which + (h&15), which: 0=w1(gate), 1=w3(up).
__global__ __launch_bounds__(256) void convert_w13_kernel(
        const float* __restrict__ w1, const float* __restrict__ w3,
        unsigned short* __restrict__ wcat) {
    const int t = threadIdx.x;
    const int e = blockIdx.y;
    const int tiles_c = NH >> 6;              // 112
    const int tr = blockIdx.x / tiles_c, tc = blockIdx.x % tiles_c;

    __shared__ unsigned short tl[64][68];
    const int rr = t >> 4, c4 = (t & 15) * 4;
    unsigned short* ob = wcat + (size_t)e * (2 * NH) * NM + (size_t)(tc * 128) * NM + tr * 64;

#pragma unroll
    for (int pass = 0; pass < 2; ++pass) {
        const float* ip = (pass ? w3 : w1) + (size_t)e * NM * NH + (size_t)(tr * 64) * NH + tc * 64;
        if (pass) __syncthreads();            // tl reuse
#pragma unroll
        for (int q = 0; q < 4; ++q) {
            const int r = q * 16 + rr;
            f32x4 v = *(const f32x4*)(ip + (size_t)r * NH + c4);
            *(u16x4*)&tl[r][c4] = (u16x4){f2bf(v[0]), f2bf(v[1]), f2bf(v[2]), f2bf(v[3])};
        }
        __syncthreads();
#pragma unroll
        for (int q = 0; q < 4; ++q) {
            const int oc = q * 16 + rr;       // h within tile
            const int orow = ((oc >> 4) * 32) + pass * 16 + (oc & 15);
            u16x4 v = (u16x4){tl[c4][oc], tl[c4 + 1][oc], tl[c4 + 2][oc], tl[c4 + 3][oc]};
            *(u16x4*)(ob + (size_t)orow * NM + c4) = v;
        }
    }
}

// =============== GEMM1 (256^2 fine-phase): hid = silu(gate)*up ===============
// A = xb [E*T][M], B = wcat [E][2H][M] (16-row gate/up interleave), K = M.
// 8 waves (2Mx4N), BK=32, 3 LDS buffers, depth-2 counted-vmcnt pipeline.
// INVARIANT (fixes r7 race): every ds_read of tile t happens AFTER the barrier
// that follows every wave's WAITV for its own tile-t loads (publish), and all
// reads of a buffer precede the end-of-iter barrier before that buffer is
// restaged (anti-dependence). WAITV(6) = A(t+1),B(t+1),A(t+2) in flight.
__global__ __launch_bounds__(512, 2) void gemm1p_kernel(
        const unsigned short* __restrict__ xb, const unsigned short* __restrict__ wcat,
        unsigned short* __restrict__ hid) {
    const int tid = threadIdx.x;
    const int lane = tid & 63, wv = tid >> 6;          // 8 waves
    const int wr = wv >> 2, wc = wv & 3;               // 2M x 4N
    const int e = blockIdx.y;
    const int d = blockIdx.x;                          // 0..447
    const int l = (d & 7) * 56 + (d >> 3);             // XCD-contiguous (448%8==0)
    const int ct = l >> 3, tt = l & 7;                 // ctile 0..55, ttile 0..7

    const unsigned short* ag = xb   + (size_t)(e * NT + tt * 256) * NM;
    const unsigned short* bg = wcat + (size_t)e * (2 * NH) * NM + (size_t)(ct * 256) * NM;
    unsigned short* hg = hid + (size_t)(e * NT + tt * 256) * NH + ct * 128;

    // 3 buf x (A 16 frags + B 16 frags) x 512 shorts = 96 KiB
    __shared__ __align__(16) unsigned short lds[3 * 16384];

    const int frow = lane & 15;            // row within frag (staging src)
    const int fks  = (lane >> 4) * 8;      // k offset within 32 (staging src)
    const int la   = lane * 8;             // shorts: lane*16B (frag-major read)
    const int lr   = lane & 15, lq = lane >> 4;

    f32x4 acc[8][4];
#pragma unroll
    for (int m = 0; m < 8; ++m)
#pragma unroll
        for (int n = 0; n < 4; ++n) acc[m][n] = (f32x4){0.f, 0.f, 0.f, 0.f};

    // wave wv stages frags wv and wv+8 (= rows f*16..f*16+15) of each tile
    auto stageA = [&](int t, int buf) {
        unsigned short* dst = lds + buf * 16384 + wv * 512;
        const unsigned short* src = ag + (size_t)(wv * 16 + frow) * NM + t * 32 + fks;
        gld16(src, dst);
        gld16(src + (size_t)128 * NM, dst + 8 * 512);
    };
    auto stageB = [&](int t, int buf) {
        unsigned short* dst = lds + buf * 16384 + 8192 + wv * 512;
        const unsigned short* src = bg + (size_t)(wv * 16 + frow) * NM + t * 32 + fks;
        gld16(src, dst);
        gld16(src + (size_t)128 * NM, dst + 8 * 512);
    };

    // body: publish-barrier, quadrant0 MFMA, stageB(t+2), quadrant1 MFMA, end-barrier
    auto body = [&](int t, int buf, bool st2, int nbuf) {
        const unsigned short* bA = lds + buf * 16384;
        const unsigned short* bB = bA + 8192;
        bf16x8 af[4], bf[4];
        BAR();                             // publish tile t (each wave WAITV'd own loads)
#pragma unroll
        for (int m = 0; m < 4; ++m)
            af[m] = *(const bf16x8*)(bA + (wr * 8 + m) * 512 + la);
#pragma unroll
        for (int n = 0; n < 4; ++n)
            bf[n] = *(const bf16x8*)(bB + (wc * 4 + n) * 512 + la);
        __builtin_amdgcn_s_setprio(1);
#pragma unroll
        for (int m = 0; m < 4; ++m)
#pragma unroll
            for (int n = 0; n < 4; ++n)
                acc[m][n] = __builtin_amdgcn_mfma_f32_16x16x32_bf16(af[m], bf[n], acc[m][n], 0, 0, 0);
        __builtin_amdgcn_s_setprio(0);
        if (st2) stageB(t + 2, nbuf);
#pragma unroll
        for (int m = 0; m < 4; ++m)
            af[m] = *(const bf16x8*)(bA + (wr * 8 + 4 + m) * 512 + la);
        __builtin_amdgcn_s_setprio(1);
#pragma unroll
        for (int m = 0; m < 4; ++m)
#pragma unroll
            for (int n = 0; n < 4; ++n)
                acc[4 + m][n] = __builtin_amdgcn_mfma_f32_16x16x32_bf16(af[m], bf[n], acc[4 + m][n], 0, 0, 0);
        __builtin_amdgcn_s_setprio(0);
        BAR();                             // all reads of buf done before restage
    };

    const int NKT = NM / 32;               // 64
    stageA(0, 0); stageB(0, 0);
    stageA(1, 1); stageB(1, 1);

    int buf = 0, nbuf = 2;
    for (int t = 0; t < NKT - 2; ++t) {
        stageA(t + 2, nbuf);
        WAITV(6);                          // own A(t),B(t) landed; 6 newer in flight
        body(t, buf, true, nbuf);
        buf = (buf == 2) ? 0 : buf + 1;
        nbuf = (nbuf == 2) ? 0 : nbuf + 1;
    }
    WAITV(4);                              // A,B(NKT-2) landed
    body(NKT - 2, buf, false, 0);
    buf = (buf == 2) ? 0 : buf + 1;
    WAITV(0);
    body(NKT - 1, buf, false, 0);

    // epilogue: N-frags alternate gate(even)/up(odd) with identical lane map
#pragma unroll
    for (int mf = 0; mf < 8; ++mf)
#pragma unroll
        for (int p = 0; p < 2; ++p)
#pragma unroll
            for (int i = 0; i < 4; ++i) {
                const float g = acc[mf][2 * p][i];
                const float u = acc[mf][2 * p + 1][i];
                const float s = g / (1.f + __expf(-g));
                const int r = wr * 128 + mf * 16 + lq * 4 + i;
                const int h = wc * 32 + p * 16 + lr;
                hg[(size_t)r * NH + h] = f2bf(s * u);
            }
}

// ================= GEMM2 (256^2 fine-phase): out = hid * w2T^T =================
// A = hid [E*T][H], B = w2t [E][M][H], K = H, fp32 out. Same pipeline.
__global__ __launch_bounds__(512, 2) void gemm2p_kernel(
        const unsigned short* __restrict__ hid, const unsigned short* __restrict__ w2t,
        float* __restrict__ out) {
    const int tid = threadIdx.x;
    const int lane = tid & 63, wv = tid >> 6;
    const int wr = wv >> 2, wc = wv & 3;
    const int e = blockIdx.y;
    const int d = blockIdx.x;                          // 0..63
    const int l = (d & 7) * 8 + (d >> 3);
    const int mt = l >> 3, tt = l & 7;                 // mtile 0..7, ttile 0..7

    const unsigned short* ag = hid + (size_t)(e * NT + tt * 256) * NH;
    const unsigned short* bg = w2t + (size_t)e * NM * NH + (size_t)(mt * 256) * NH;
    float* og = out + (size_t)(e * NT + tt * 256) * NM + mt * 256;

    __shared__ __align__(16) unsigned short lds[3 * 16384];

    const int frow = lane & 15;
    const int fks  = (lane >> 4) * 8;
    const int la   = lane * 8;
    const int lr   = lane & 15, lq = lane >> 4;

    f32x4 acc[8][4];
#pragma unroll
    for (int m = 0; m < 8; ++m)
#pragma unroll
        for (int n = 0; n < 4; ++n) acc[m][n] = (f32x4){0.f, 0.f, 0.f, 0.f};

    auto stageA = [&](int t, int buf) {
        unsigned short* dst = lds + buf * 16384 + wv * 512;
        const unsigned short* src = ag + (size_t)(wv * 16 + frow) * NH + t * 32 + fks;
        gld16(src, dst);
        gld16(src + (size_t)128 * NH, dst + 8 * 512);
    };
    auto stageB = [&](int t, int buf) {
        unsigned short* dst = lds + buf * 16384 + 8192 + wv * 512;
        const unsigned short* src = bg + (size_t)(wv * 16 + frow) * NH + t * 32 + fks;
        gld16(src, dst);
        gld16(src + (size_t)128 * NH, dst + 8 * 512);
    };

    auto body = [&](int t, int buf, bool st2, int nbuf) {
        const unsigned short* bA = lds + buf * 16384;
        const unsigned short* bB = bA + 8192;
        bf16x8 af[4], bf[4];
        BAR();
#pragma unroll
        for (int m = 0; m < 4; ++m)
            af[m] = *(const bf16x8*)(bA + (wr * 8 + m) * 512 + la);
#pragma unroll
        for (int n = 0; n < 4; ++n)
            bf[n] = *(const bf16x8*)(bB + (wc * 4 + n) * 512 + la);
        __builtin_amdgcn_s_setprio(1);
#pragma unroll
        for (int m = 0; m < 4; ++m)
#pragma unroll
            for (int n = 0; n < 4; ++n)
                acc[m][n] = __builtin_amdgcn_mfma_f32_16x16x32_bf16(af[m], bf[n], acc[m][n], 0, 0, 0);
        __builtin_amdgcn_s_setprio(0);
        if (st2) stageB(t + 2, nbuf);
#pragma unroll
        for (int m = 0; m < 4; ++m)
            af[m] = *(const bf16x8*)(bA + (wr * 8 + 4 + m) * 512 + la);
        __builtin_amdgcn_s_setprio(1);
#pragma unroll
        for (int m = 0; m < 4; ++m)
#pragma unroll
            for (int n = 0; n < 4; ++n)
                acc[4 + m][n] = __builtin_amdgcn_mfma_f32_16x16x32_bf16(af[m], bf[n], acc[4 + m][n], 0, 0, 0);
        __builtin_amdgcn_s_setprio(0);
        BAR();
    };

    const int NKT = NH / 32;               // 224
    stageA(0, 0); stageB(0, 0);
    stageA(1, 1); stageB(1, 1);

    int buf = 0, nbuf = 2;
    for (int t = 0; t < NKT - 2; ++t) {
        stageA(t + 2, nbuf);
        WAITV(6);
        body(t, buf, true, nbuf);
        buf = (buf == 2) ? 0 : buf + 1;
        nbuf = (nbuf == 2) ? 0 : nbuf + 1;
    }
    WAITV(4);
    body(NKT - 2, buf, false, 0);
    buf = (buf == 2) ? 0 : buf + 1;
    WAITV(0);
    body(NKT - 1, buf, false, 0);

#pragma unroll
    for (int mf = 0; mf < 8; ++mf)
#pragma unroll
        for (int n = 0; n < 4; ++n)
#pragma unroll
            for (int i = 0; i < 4; ++i) {
                const int r = wr * 128 + mf * 16 + lq * 4 + i;
                const int c = wc * 64 + n * 16 + lr;
                og[(size_t)r * NM + c] = acc[mf][n][i];
            }
}

// ===================== fallback (round-1, fused-convert) =====================
#define ROWB 80
#define TILEB (128 * ROWB)

__global__ __launch_bounds__(256, 2) void gemm1_fb_kernel(
        const float* __restrict__ x, const float* __restrict__ w1,
        const float* __restrict__ w3, unsigned short* __restrict__ hid) {
    const int tid = threadIdx.x;
    const int e = blockIdx.y;
    const int d = blockIdx.x;
    const int l = (d & 7) * 112 + (d >> 3);
    const int hn = l >> 4, tm = l & 15;

    const float* xg  = x  + (size_t)(e * NT + tm * 128) * NM;
    const float* w1g = w1 + (size_t)e * NM * NH + hn * 128;
    const float* w3g = w3 + (size_t)e * NM * NH + hn * 128;
    unsigned short* hg = hid + (size_t)(e * NT + tm * 128) * NH + hn * 128;

    __shared__ __align__(16) unsigned char lds[2 * 3 * TILEB];

    const int a_r = tid >> 3, a_c4 = tid & 7;
    const int w_kq = (tid >> 2) & 7;
    const int w_cg = ((tid >> 5) << 2) | (tid & 3);

    const int lane = tid & 63;
    const int wv = tid >> 6;
    const int r0w = (wv >> 1) * 64, c0w = (wv & 1) * 64;
    const int lr = lane & 15, lq = lane >> 4;

    f32x4 accg[4][4], accu[4][4];
#pragma unroll
    for (int m = 0; m < 4; ++m)
#pragma unroll
        for (int n = 0; n < 4; ++n) {
            accg[m][n] = (f32x4){0.f, 0.f, 0.f, 0.f};
            accu[m][n] = (f32x4){0.f, 0.f, 0.f, 0.f};
        }

    f32x4 la0, la1, la2, la3;
    f32x4 l10, l11, l12, l13, l30, l31, l32, l33;

    auto stage_load = [&](int ks) {
        const int k0 = ks * 32;
        const float* pa = xg + (size_t)a_r * NM + k0 + a_c4 * 4;
        la0 = *(const f32x4*)(pa);
        la1 = *(const f32x4*)(pa + 32 * NM);
        la2 = *(const f32x4*)(pa + 64 * NM);
        la3 = *(const f32x4*)(pa + 96 * NM);
        const float* p1 = w1g + (size_t)(k0 + w_kq * 4) * NH + w_cg * 4;
        l10 = *(const f32x4*)(p1);
        l11 = *(const f32x4*)(p1 + NH);
        l12 = *(const f32x4*)(p1 + 2 * NH);
        l13 = *(const f32x4*)(p1 + 3 * NH);
        const float* p3 = w3g + (size_t)(k0 + w_kq * 4) * NH + w_cg * 4;
        l30 = *(const f32x4*)(p3);
        l31 = *(const f32x4*)(p3 + NH);
        l32 = *(const f32x4*)(p3 + 2 * NH);
        l33 = *(const f32x4*)(p3 + 3 * NH);
    };

    auto stage_write = [&](int buf) {
        unsigned char* base = lds + buf * (3 * TILEB);
        unsigned char* pa = base + a_r * ROWB + a_c4 * 8;
        *(u16x4*)(pa)             = (u16x4){f2bf(la0[0]), f2bf(la0[1]), f2bf(la0[2]), f2bf(la0[3])};
        *(u16x4*)(pa + 32 * ROWB) = (u16x4){f2bf(la1[0]), f2bf(la1[1]), f2bf(la1[2]), f2bf(la1[3])};
        *(u16x4*)(pa + 64 * ROWB) = (u16x4){f2bf(la2[0]), f2bf(la2[1]), f2bf(la2[2]), f2bf(la2[3])};
        *(u16x4*)(pa + 96 * ROWB) = (u16x4){f2bf(la3[0]), f2bf(la3[1]), f2bf(la3[2]), f2bf(la3[3])};
        unsigned char* pw1 = base + TILEB + w_kq * 8;
#pragma unroll
        for (int j = 0; j < 4; ++j) {
            const int c = w_cg * 4 + j;
            *(u16x4*)(pw1 + c * ROWB) =
                (u16x4){f2bf(l10[j]), f2bf(l11[j]), f2bf(l12[j]), f2bf(l13[j])};
        }
        unsigned char* pw3 = base + 2 * TILEB + w_kq * 8;
#pragma unroll
        for (int j = 0; j < 4; ++j) {
            const int c = w_cg * 4 + j;
            *(u16x4*)(pw3 + c * ROWB) =
                (u16x4){f2bf(l30[j]), f2bf(l31[j]), f2bf(l32[j]), f2bf(l33[j])};
        }
    };

    auto compute = [&](int buf) {
        const unsigned char* base = lds + buf * (3 * TILEB);
        bf16x8 af[4], b1f[4], b3f[4];
#pragma unroll
        for (int m = 0; m < 4; ++m)
            af[m] = *(const bf16x8*)(base + (r0w + m * 16 + lr) * ROWB + lq * 16);
#pragma unroll
        for (int n = 0; n < 4; ++n) {
            b1f[n] = *(const bf16x8*)(base + TILEB + (c0w + n * 16 + lr) * ROWB + lq * 16);
            b3f[n] = *(const bf16x8*)(base + 2 * TILEB + (c0w + n * 16 + lr) * ROWB + lq * 16);
        }
#pragma unroll
        for (int m = 0; m < 4; ++m)
#pragma unroll
            for (int n = 0; n < 4; ++n) {
                accg[m][n] = __builtin_amdgcn_mfma_f32_16x16x32_bf16(af[m], b1f[n], accg[m][n], 0, 0, 0);
                accu[m][n] = __builtin_amdgcn_mfma_f32_16x16x32_bf16(af[m], b3f[n], accu[m][n], 0, 0, 0);
            }
    };

    stage_load(0);
    stage_write(0);
    __syncthreads();
    int cur = 0;
    const int NK = NM / 32;
    for (int ks = 0; ks < NK; ++ks) {
        const bool more = (ks + 1 < NK);
        if (more) stage_load(ks + 1);
        compute(cur);
        if (more) {
            stage_write(cur ^ 1);
            __syncthreads();
        }
        cur ^= 1;
    }

#pragma unroll
    for (int m = 0; m < 4; ++m)
#pragma unroll
        for (int n = 0; n < 4; ++n)
#pragma unroll
            for (int i = 0; i < 4; ++i) {
                const float g = accg[m][n][i];
                const float u = accu[m][n][i];
                const float s = g / (1.f + __expf(-g));
                const int r = r0w + m * 16 + lq * 4 + i;
                const int c = c0w + n * 16 + lr;
                hg[(size_t)r * NH + c] = f2bf(s * u);
            }
}

__global__ __launch_bounds__(256, 2) void gemm2_fb_kernel(
        const unsigned short* __restrict__ hid, const float* __restrict__ w2,
        float* __restrict__ out) {
    const int tid = threadIdx.x;
    const int e = blockIdx.y;
    const int d = blockIdx.x;
    const int l = (d & 7) * 32 + (d >> 3);
    const int mn = l >> 4, tm = l & 15;

    const unsigned short* ag = hid + (size_t)(e * NT + tm * 128) * NH;
    const float* wg = w2 + (size_t)e * NH * NM + mn * 128;
    float* og = out + (size_t)(e * NT + tm * 128) * NM + mn * 128;

    __shared__ __align__(16) unsigned char lds[2 * 2 * TILEB];

    const int a_row = tid >> 2, a_ch = tid & 3;
    const int w_kq = (tid >> 2) & 7;
    const int w_cg = ((tid >> 5) << 2) | (tid & 3);

    const int lane = tid & 63;
    const int wv = tid >> 6;
    const int r0w = (wv >> 1) * 64, c0w = (wv & 1) * 64;
    const int lr = lane & 15, lq = lane >> 4;

    f32x4 acc[4][4];
#pragma unroll
    for (int m = 0; m < 4; ++m)
#pragma unroll
        for (int n = 0; n < 4; ++n) acc[m][n] = (f32x4){0.f, 0.f, 0.f, 0.f};

    u32x4 lau0, lau1;
    f32x4 lw0, lw1, lw2, lw3;

    auto stage_load = [&](int ks) {
        const int k0 = ks * 32;
        lau0 = *(const u32x4*)(ag + (size_t)a_row * NH + k0 + a_ch * 8);
        lau1 = *(const u32x4*)(ag + (size_t)(a_row + 64) * NH + k0 + a_ch * 8);
        const float* p = wg + (size_t)(k0 + w_kq * 4) * NM + w_cg * 4;
        lw0 = *(const f32x4*)(p);
        lw1 = *(const f32x4*)(p + NM);
        lw2 = *(const f32x4*)(p + 2 * NM);
        lw3 = *(const f32x4*)(p + 3 * NM);
    };

    auto stage_write = [&](int buf) {
        unsigned char* base = lds + buf * (2 * TILEB);
        *(u32x4*)(base + a_row * ROWB + a_ch * 16) = lau0;
        *(u32x4*)(base + (a_row + 64) * ROWB + a_ch * 16) = lau1;
        unsigned char* pw = base + TILEB + w_kq * 8;
#pragma unroll
        for (int j = 0; j < 4; ++j) {
            const int c = w_cg * 4 + j;
            *(u16x4*)(pw + c * ROWB) =
                (u16x4){f2bf(lw0[j]), f2bf(lw1[j]), f2bf(lw2[j]), f2bf(lw3[j])};
        }
    };

    auto compute = [&](int buf) {
        const unsigned char* base = lds + buf * (2 * TILEB);
        bf16x8 af[4], bf[4];
#pragma unroll
        for (int m = 0; m < 4; ++m)
            af[m] = *(const bf16x8*)(base + (r0w + m * 16 + lr) * ROWB + lq * 16);
#pragma unroll
        for (int n = 0; n < 4; ++n)
            bf[n] = *(const bf16x8*)(base + TILEB + (c0w + n * 16 + lr) * ROWB + lq * 16);
#pragma unroll
        for (int m = 0; m < 4; ++m)
#pragma unroll
            for (int n = 0; n < 4; ++n)
                acc[m][n] = __builtin_amdgcn_mfma_f32_16x16x32_bf16(af[m], bf[n], acc[m][n], 0, 0, 0);
    };

    stage_load(0);
    stage_write(0);
    __syncthreads();
    int cur = 0;
    const int NK = NH / 32;
    for (int ks = 0; ks < NK; ++ks) {
        const bool more = (ks + 1 < NK);
        if (more) stage_load(ks + 1);
        compute(cur);
        if (more) {
            stage_write(cur ^ 1);
            __syncthreads();
        }
        cur ^= 1;
    }

#pragma unroll
    for (int m = 0; m < 4; ++m)
#pragma unroll
        for (int n = 0; n < 4; ++n)
#pragma unroll
            for (int i = 0; i < 4; ++i) {
                const int r = r0w + m * 16 + lq * 4 + i;
                const int c = c0w + n * 16 + lr;
                og[(size_t)r * NM + c] = acc[m][n][i];
            }
}

// ================================ launcher ================================

extern "C" void kernel_launch(void* const* d_in, const int* in_sizes, int n_in,
                              void* d_out, int out_size, void* d_ws, size_t ws_size,
                              hipStream_t stream) {
    const float* x  = (const float*)d_in[0];
    const float* w1 = (const float*)d_in[1];
    const float* w2 = (const float*)d_in[2];
    const float* w3 = (const float*)d_in[3];
    float* out = (float*)d_out;

    const size_t XB_SZ   = (size_t)NE * NT * NM * 2;        //  64 MiB
    const size_t WCAT_SZ = (size_t)NE * 2 * NH * NM * 2;    // 448 MiB
    const size_t HID_SZ  = (size_t)NE * NT * NH * 2;        // 224 MiB
    const size_t NEED = XB_SZ + WCAT_SZ + HID_SZ;           // 736 MiB

    if (ws_size >= NEED) {
        unsigned char* ws = (unsigned char*)d_ws;
        unsigned short* xbp  = (unsigned short*)(ws);
        unsigned short* wcat = (unsigned short*)(ws + XB_SZ);
        unsigned short* hidb = (unsigned short*)(ws + XB_SZ + WCAT_SZ);
        unsigned short* w2t  = (unsigned short*)(ws);   // reuses xb/wcat after gemm1

        convert_x_kernel<<<dim3((NE * NT * NM) / 1024), 256, 0, stream>>>(x, xbp);
        convert_w13_kernel<<<dim3((NM / 64) * (NH / 64), NE), 256, 0, stream>>>(w1, w3, wcat);
        gemm1p_kernel<<<dim3(448, NE), 512, 0, stream>>>(xbp, wcat, hidb);
        convert_wT_kernel<<<dim3((NH / 64) * (NM / 64), NE), 256, 0, stream>>>(w2, w2t, NH, NM);
        gemm2p_kernel<<<dim3(64, NE), 512, 0, stream>>>(hidb, w2t, out);
    } else {
        unsigned short* hid = (unsigned short*)d_ws;
        gemm1_fb_kernel<<<dim3(896, NE), 256, 0, stream>>>(x, w1, w3, hid);
        gemm2_fb_kernel<<<dim3(256, NE), 256, 0, stream>>>(hid, w2, out);
    }
}